// Round 16
// baseline (236.895 us; speedup 1.0000x reference)
//
#include <hip/hip_runtime.h>
#include <hip/hip_bf16.h>

#define NNODES 8192
#define EMB    1024
#define HID    256
#define MAXDEG 128

typedef float f32x4 __attribute__((ext_vector_type(4)));
typedef short bf16x8v __attribute__((ext_vector_type(8)));
typedef unsigned short u16x4 __attribute__((ext_vector_type(4)));
typedef unsigned short u16x8 __attribute__((ext_vector_type(8)));

static __device__ __forceinline__ unsigned short f2bf(float f) {
  union { float f; unsigned int u; } x; x.f = f;
  unsigned int r = (x.u + 0x7fffu + ((x.u >> 16) & 1u)) >> 16;
  return (unsigned short)r;
}
static __device__ __forceinline__ float bf2f(unsigned short u) {
  union { unsigned int u; float f; } x; x.u = ((unsigned int)u) << 16;
  return x.f;
}

// ---------------------------------------------------------------------------
// Prep: Wt[n][k] = bf16(W[k][n]).  64x64 f32 tiles via LDS transpose.
// ---------------------------------------------------------------------------
__global__ __launch_bounds__(256) void prep_wt(const float* __restrict__ W,
                                               unsigned short* __restrict__ Wt) {
  __shared__ float lds[64 * 65];
  int k0 = (blockIdx.x >> 2) * 64;
  int n0 = (blockIdx.x & 3) * 64;
  int t = threadIdx.x;
#pragma unroll
  for (int p = 0; p < 4; p++) {
    int k = p * 16 + (t >> 4);
    int c4 = (t & 15) * 4;
    float4 v = *(const float4*)&W[(size_t)(k0 + k) * HID + n0 + c4];
    lds[k * 65 + c4 + 0] = v.x; lds[k * 65 + c4 + 1] = v.y;
    lds[k * 65 + c4 + 2] = v.z; lds[k * 65 + c4 + 3] = v.w;
  }
  __syncthreads();
  int n = t >> 2, kq = t & 3;
  u16x8 o0, o1;
#pragma unroll
  for (int i = 0; i < 8; i++) o0[i] = f2bf(lds[(kq * 16 + i) * 65 + n]);
#pragma unroll
  for (int i = 0; i < 8; i++) o1[i] = f2bf(lds[(kq * 16 + 8 + i) * 65 + n]);
  unsigned short* dst = &Wt[(size_t)(n0 + n) * EMB + k0 + kq * 16];
  *(u16x8*)(dst) = o0;
  *(u16x8*)(dst + 8) = o1;
}

// ---------------------------------------------------------------------------
// Fused (R15 verbatim): blocks [0,256) = bf16-MFMA GEMM 128x64 tile;
// blocks [256, 256+8192) = extract with 8 batched nontemporal loads.
// ---------------------------------------------------------------------------
#define GEMM_BLOCKS 256

__global__ __launch_bounds__(256) void fused_extract_gemm(
    const float* __restrict__ X, const unsigned short* __restrict__ Wt,
    const float* __restrict__ bias, const float* __restrict__ adj,
    unsigned short* __restrict__ hb0, float* __restrict__ dinv,
    int* __restrict__ nnz, int* __restrict__ cols, float* __restrict__ vals) {
  __shared__ char smem[24 * 1024 + 64];
  int t = threadIdx.x;

  if (blockIdx.x >= GEMM_BLOCKS) {
    // ---------------- extract path ----------------
    int row = blockIdx.x - GEMM_BLOCKS;
    int* s_cnt = (int*)smem;
    float* s_part = (float*)(smem + 16);
    if (t == 0) *s_cnt = 0;
    __syncthreads();
    const f32x4* arow = (const f32x4*)(adj + (size_t)row * NNODES);
    int base = row * MAXDEG;

    f32x4 v[8];
#pragma unroll
    for (int i = 0; i < 8; i++)
      v[i] = __builtin_nontemporal_load(arow + i * 256 + t);

    float sum = 0.f;
#pragma unroll
    for (int i = 0; i < 8; i++) {
      sum += v[i].x + v[i].y + v[i].z + v[i].w;
      int j0 = (i * 256 + t) * 4;
      if (v[i].x != 0.f) { int p = atomicAdd(s_cnt, 1); if (p < MAXDEG) { cols[base + p] = j0 + 0; vals[base + p] = v[i].x; } }
      if (v[i].y != 0.f) { int p = atomicAdd(s_cnt, 1); if (p < MAXDEG) { cols[base + p] = j0 + 1; vals[base + p] = v[i].y; } }
      if (v[i].z != 0.f) { int p = atomicAdd(s_cnt, 1); if (p < MAXDEG) { cols[base + p] = j0 + 2; vals[base + p] = v[i].z; } }
      if (v[i].w != 0.f) { int p = atomicAdd(s_cnt, 1); if (p < MAXDEG) { cols[base + p] = j0 + 3; vals[base + p] = v[i].w; } }
    }
    for (int off = 32; off > 0; off >>= 1) sum += __shfl_down(sum, off, 64);
    int wave = t >> 6;
    if ((t & 63) == 0) s_part[wave] = sum;
    __syncthreads();
    if (t == 0) {
      float tot = s_part[0] + s_part[1] + s_part[2] + s_part[3];
      dinv[row] = rsqrtf(tot);
      int c = *s_cnt;
      nnz[row] = (c > MAXDEG) ? MAXDEG : c;
    }
    return;
  }

  // ---------------- GEMM path: 128x64 tile, BK=64, bf16 MFMA ----------------
  unsigned short* As = (unsigned short*)smem;               // [128][64] bf16
  unsigned short* Bs = (unsigned short*)(smem + 16 * 1024); // [64][64] bf16 (B^T)
  int mb = blockIdx.x >> 2, nb = blockIdx.x & 3;
  int m0 = mb * 128, n0 = nb * 64;
  int w = t >> 6, l = t & 63;

  f32x4 acc[2][4] = {};

  for (int kt = 0; kt < EMB; kt += 64) {
    __syncthreads();
    {
      int c4 = t & 15;
#pragma unroll
      for (int rr = 0; rr < 8; rr++) {
        int row = rr * 16 + (t >> 4);
        float4 v = *(const float4*)&X[(size_t)(m0 + row) * EMB + kt + c4 * 4];
        u16x4 pk = {f2bf(v.x), f2bf(v.y), f2bf(v.z), f2bf(v.w)};
        int slot = ((c4 >> 1) + (row >> 1)) & 7;
        *(u16x4*)&As[row * 64 + slot * 8 + (c4 & 1) * 4] = pk;
      }
    }
    {
      int n = t >> 2, q = t & 3;
      const unsigned short* src = &Wt[(size_t)(n0 + n) * EMB + kt + q * 16];
#pragma unroll
      for (int e = 0; e < 2; e++) {
        u16x8 v = *(const u16x8*)(src + e * 8);
        int slot = ((q * 2 + e) + (n >> 1)) & 7;
        *(u16x8*)&Bs[n * 64 + slot * 8] = v;
      }
    }
    __syncthreads();
#pragma unroll
    for (int ks = 0; ks < 2; ks++) {
      bf16x8v a[2], b[4];
#pragma unroll
      for (int mf = 0; mf < 2; mf++) {
        int row = w * 32 + mf * 16 + (l & 15);
        int slot = ((ks * 4 + (l >> 4)) + (row >> 1)) & 7;
        a[mf] = *(bf16x8v*)&As[row * 64 + slot * 8];
      }
#pragma unroll
      for (int nf = 0; nf < 4; nf++) {
        int rowB = nf * 16 + (l & 15);
        int slot = ((ks * 4 + (l >> 4)) + (rowB >> 1)) & 7;
        b[nf] = *(bf16x8v*)&Bs[rowB * 64 + slot * 8];
      }
#pragma unroll
      for (int mf = 0; mf < 2; mf++)
#pragma unroll
        for (int nf = 0; nf < 4; nf++)
          acc[mf][nf] = __builtin_amdgcn_mfma_f32_16x16x32_bf16(a[mf], b[nf], acc[mf][nf], 0, 0, 0);
    }
  }
#pragma unroll
  for (int mf = 0; mf < 2; mf++)
#pragma unroll
    for (int nf = 0; nf < 4; nf++) {
      int r0 = m0 + w * 32 + mf * 16 + (l >> 4) * 4;
      int cc = n0 + nf * 16 + (l & 15);
      float bv = bias[cc];
#pragma unroll
      for (int r = 0; r < 4; r++)
        hb0[(size_t)(r0 + r) * HID + cc] = f2bf(fmaxf(acc[mf][nf][r] + bv, 0.f));
    }
}

// ---------------------------------------------------------------------------
// One APPNP step; 8 consecutive rows per wave (grid 256 blocks, 8x fewer than
// R15 -> less ramp overhead). Metadata for all 8 rows batch-loaded up front;
// per-row poison-safe <=4-edge fast path, serial tail for rare n>4.
// ---------------------------------------------------------------------------
template <int FINAL>
__global__ __launch_bounds__(256) void prop_step_t(
    const unsigned short* __restrict__ h_in, const unsigned short* __restrict__ hb0,
    void* __restrict__ h_out_v, const float* __restrict__ dinv,
    const int* __restrict__ nnz, const int* __restrict__ cols,
    const float* __restrict__ vals) {
  int wave = threadIdx.x >> 6;
  int lane = threadIdx.x & 63;
  int rbase = (blockIdx.x * 4 + wave) * 8;

  // batch metadata loads (all independent)
  int4   cv[8];
  float4 vv[8];
  int    nn[8];
#pragma unroll
  for (int r = 0; r < 8; r++) {
    cv[r] = *(const int4*)&cols[(rbase + r) * MAXDEG];
    vv[r] = *(const float4*)&vals[(rbase + r) * MAXDEG];
    nn[r] = nnz[rbase + r];
  }

#pragma unroll
  for (int r = 0; r < 8; r++) {
    int row = rbase + r;
    int n = nn[r];

    int jj[4]; float ww[4];
    jj[0] = (0 < n) ? cv[r].x : row;  ww[0] = (0 < n) ? vv[r].x : 0.f;
    jj[1] = (1 < n) ? cv[r].y : row;  ww[1] = (1 < n) ? vv[r].y : 0.f;
    jj[2] = (2 < n) ? cv[r].z : row;  ww[2] = (2 < n) ? vv[r].z : 0.f;
    jj[3] = (3 < n) ? cv[r].w : row;  ww[3] = (3 < n) ? vv[r].w : 0.f;

    float ax = 0.f, ay = 0.f, az = 0.f, aw = 0.f;
#pragma unroll
    for (int k = 0; k < 4; k++) {
      float wgt = ww[k] * dinv[jj[k]];
      u16x4 hv = *(const u16x4*)&h_in[(size_t)jj[k] * HID + lane * 4];
      ax += wgt * bf2f(hv[0]); ay += wgt * bf2f(hv[1]);
      az += wgt * bf2f(hv[2]); aw += wgt * bf2f(hv[3]);
    }
    int base = row * MAXDEG;
    for (int k = 4; k < n; k++) {          // rare
      int j = cols[base + k];
      float wgt = vals[base + k] * dinv[j];
      u16x4 hv = *(const u16x4*)&h_in[(size_t)j * HID + lane * 4];
      ax += wgt * bf2f(hv[0]); ay += wgt * bf2f(hv[1]);
      az += wgt * bf2f(hv[2]); aw += wgt * bf2f(hv[3]);
    }
    float s = 0.8f * dinv[row];
    u16x4 h0v = *(const u16x4*)&hb0[(size_t)row * HID + lane * 4];
    if (FINAL) {
      float4 o;
      o.x = s * ax + 0.2f * bf2f(h0v[0]);
      o.y = s * ay + 0.2f * bf2f(h0v[1]);
      o.z = s * az + 0.2f * bf2f(h0v[2]);
      o.w = s * aw + 0.2f * bf2f(h0v[3]);
      *(float4*)&((float*)h_out_v)[(size_t)row * HID + lane * 4] = o;
    } else {
      u16x4 o;
      o[0] = f2bf(s * ax + 0.2f * bf2f(h0v[0]));
      o[1] = f2bf(s * ay + 0.2f * bf2f(h0v[1]));
      o[2] = f2bf(s * az + 0.2f * bf2f(h0v[2]));
      o[3] = f2bf(s * aw + 0.2f * bf2f(h0v[3]));
      *(u16x4*)&((unsigned short*)h_out_v)[(size_t)row * HID + lane * 4] = o;
    }
  }
}

// ---------------------------------------------------------------------------
extern "C" void kernel_launch(void* const* d_in, const int* in_sizes, int n_in,
                              void* d_out, int out_size, void* d_ws, size_t ws_size,
                              hipStream_t stream) {
  const float* X    = (const float*)d_in[0];  // [8192,1024]
  const float* W    = (const float*)d_in[1];  // [1024,256]
  const float* bias = (const float*)d_in[2];  // [256]
  const float* adj  = (const float*)d_in[3];  // [8192,8192]
  float* out = (float*)d_out;                 // [8192,256]

  char* ws = (char*)d_ws;
  unsigned short* hb0  = (unsigned short*)(ws);                           // 4 MB
  unsigned short* hb1  = (unsigned short*)(ws + (size_t)4 * 1024 * 1024); // 4 MB
  unsigned short* hb2  = (unsigned short*)(ws + (size_t)8 * 1024 * 1024); // 4 MB
  float* dinv = (float*)(ws + (size_t)12 * 1024 * 1024);                  // 32 KB
  int*   nnz  = (int*)  (ws + (size_t)12 * 1024 * 1024 + 32 * 1024);      // 32 KB
  int*   cols = (int*)  (ws + (size_t)12 * 1024 * 1024 + 64 * 1024);      // 4 MB
  float* vals = (float*)(ws + (size_t)16 * 1024 * 1024 + 64 * 1024);      // 4 MB
  unsigned short* Wt = (unsigned short*)(ws + (size_t)20 * 1024 * 1024
                                            + 64 * 1024);                 // 512 KB

  prep_wt<<<64, 256, 0, stream>>>(W, Wt);
  fused_extract_gemm<<<GEMM_BLOCKS + NNODES, 256, 0, stream>>>(
      X, Wt, bias, adj, hb0, dinv, nnz, cols, vals);

  // 5 bf16 steps ping-ponging hb1/hb2, then final f32 step into d_out.
  prop_step_t<0><<<NNODES / 32, 256, 0, stream>>>(hb0, hb0, hb1, dinv, nnz, cols, vals);
  prop_step_t<0><<<NNODES / 32, 256, 0, stream>>>(hb1, hb0, hb2, dinv, nnz, cols, vals);
  prop_step_t<0><<<NNODES / 32, 256, 0, stream>>>(hb2, hb0, hb1, dinv, nnz, cols, vals);
  prop_step_t<0><<<NNODES / 32, 256, 0, stream>>>(hb1, hb0, hb2, dinv, nnz, cols, vals);
  prop_step_t<0><<<NNODES / 32, 256, 0, stream>>>(hb2, hb0, hb1, dinv, nnz, cols, vals);
  prop_step_t<1><<<NNODES / 32, 256, 0, stream>>>(hb1, hb0, out, dinv, nnz, cols, vals);
}

// Round 17
// 120.285 us; speedup vs baseline: 1.9694x; 1.9694x over previous
//
#include <hip/hip_runtime.h>
#include <hip/hip_bf16.h>

#define NNODES 8192
#define EMB    1024
#define HID    256
#define MAXDEG 128

typedef float f32x4 __attribute__((ext_vector_type(4)));
typedef short bf16x8v __attribute__((ext_vector_type(8)));
typedef unsigned short u16x4 __attribute__((ext_vector_type(4)));
typedef unsigned short u16x8 __attribute__((ext_vector_type(8)));

static __device__ __forceinline__ unsigned short f2bf(float f) {
  union { float f; unsigned int u; } x; x.f = f;
  unsigned int r = (x.u + 0x7fffu + ((x.u >> 16) & 1u)) >> 16;
  return (unsigned short)r;
}
static __device__ __forceinline__ float bf2f(unsigned short u) {
  union { unsigned int u; float f; } x; x.u = ((unsigned int)u) << 16;
  return x.f;
}

// ---------------------------------------------------------------------------
// Prep: Wt[n][k] = bf16(W[k][n]).  64x64 f32 tiles via LDS transpose.
// ---------------------------------------------------------------------------
__global__ __launch_bounds__(256) void prep_wt(const float* __restrict__ W,
                                               unsigned short* __restrict__ Wt) {
  __shared__ float lds[64 * 65];
  int k0 = (blockIdx.x >> 2) * 64;
  int n0 = (blockIdx.x & 3) * 64;
  int t = threadIdx.x;
#pragma unroll
  for (int p = 0; p < 4; p++) {
    int k = p * 16 + (t >> 4);
    int c4 = (t & 15) * 4;
    float4 v = *(const float4*)&W[(size_t)(k0 + k) * HID + n0 + c4];
    lds[k * 65 + c4 + 0] = v.x; lds[k * 65 + c4 + 1] = v.y;
    lds[k * 65 + c4 + 2] = v.z; lds[k * 65 + c4 + 3] = v.w;
  }
  __syncthreads();
  int n = t >> 2, kq = t & 3;
  u16x8 o0, o1;
#pragma unroll
  for (int i = 0; i < 8; i++) o0[i] = f2bf(lds[(kq * 16 + i) * 65 + n]);
#pragma unroll
  for (int i = 0; i < 8; i++) o1[i] = f2bf(lds[(kq * 16 + 8 + i) * 65 + n]);
  unsigned short* dst = &Wt[(size_t)(n0 + n) * EMB + k0 + kq * 16];
  *(u16x8*)(dst) = o0;
  *(u16x8*)(dst + 8) = o1;
}

// ---------------------------------------------------------------------------
// Fused: blocks [0,256) = bf16-MFMA GEMM 128x64 tile (R15 verbatim);
// blocks [256, 256+4096) = extract, TWO adj rows per block with 16 batched
// nontemporal loads (extract inherits the GEMM path's VGPR allocation, so
// the extra batch registers are free; doubles bytes-in-flight per block).
// ---------------------------------------------------------------------------
#define GEMM_BLOCKS 256

__global__ __launch_bounds__(256) void fused_extract_gemm(
    const float* __restrict__ X, const unsigned short* __restrict__ Wt,
    const float* __restrict__ bias, const float* __restrict__ adj,
    unsigned short* __restrict__ hb0, float* __restrict__ dinv,
    int* __restrict__ nnz, int* __restrict__ cols, float* __restrict__ vals) {
  __shared__ char smem[24 * 1024 + 64];
  int t = threadIdx.x;

  if (blockIdx.x >= GEMM_BLOCKS) {
    // ---------------- extract path: 2 rows per block ----------------
    int row0 = (blockIdx.x - GEMM_BLOCKS) * 2;
    int row1 = row0 + 1;
    int* s_cnt = (int*)smem;            // [2]
    float* s_part = (float*)(smem + 16); // [8]
    if (t < 2) s_cnt[t] = 0;
    __syncthreads();
    const f32x4* a0 = (const f32x4*)(adj + (size_t)row0 * NNODES);
    const f32x4* a1 = (const f32x4*)(adj + (size_t)row1 * NNODES);
    int base0 = row0 * MAXDEG, base1 = row1 * MAXDEG;

    f32x4 v0[8], v1[8];
#pragma unroll
    for (int i = 0; i < 8; i++) v0[i] = __builtin_nontemporal_load(a0 + i * 256 + t);
#pragma unroll
    for (int i = 0; i < 8; i++) v1[i] = __builtin_nontemporal_load(a1 + i * 256 + t);

    float sum0 = 0.f, sum1 = 0.f;
#pragma unroll
    for (int i = 0; i < 8; i++) {
      sum0 += v0[i].x + v0[i].y + v0[i].z + v0[i].w;
      int j0 = (i * 256 + t) * 4;
      if (v0[i].x != 0.f) { int p = atomicAdd(&s_cnt[0], 1); if (p < MAXDEG) { cols[base0 + p] = j0 + 0; vals[base0 + p] = v0[i].x; } }
      if (v0[i].y != 0.f) { int p = atomicAdd(&s_cnt[0], 1); if (p < MAXDEG) { cols[base0 + p] = j0 + 1; vals[base0 + p] = v0[i].y; } }
      if (v0[i].z != 0.f) { int p = atomicAdd(&s_cnt[0], 1); if (p < MAXDEG) { cols[base0 + p] = j0 + 2; vals[base0 + p] = v0[i].z; } }
      if (v0[i].w != 0.f) { int p = atomicAdd(&s_cnt[0], 1); if (p < MAXDEG) { cols[base0 + p] = j0 + 3; vals[base0 + p] = v0[i].w; } }
    }
#pragma unroll
    for (int i = 0; i < 8; i++) {
      sum1 += v1[i].x + v1[i].y + v1[i].z + v1[i].w;
      int j0 = (i * 256 + t) * 4;
      if (v1[i].x != 0.f) { int p = atomicAdd(&s_cnt[1], 1); if (p < MAXDEG) { cols[base1 + p] = j0 + 0; vals[base1 + p] = v1[i].x; } }
      if (v1[i].y != 0.f) { int p = atomicAdd(&s_cnt[1], 1); if (p < MAXDEG) { cols[base1 + p] = j0 + 1; vals[base1 + p] = v1[i].y; } }
      if (v1[i].z != 0.f) { int p = atomicAdd(&s_cnt[1], 1); if (p < MAXDEG) { cols[base1 + p] = j0 + 2; vals[base1 + p] = v1[i].z; } }
      if (v1[i].w != 0.f) { int p = atomicAdd(&s_cnt[1], 1); if (p < MAXDEG) { cols[base1 + p] = j0 + 3; vals[base1 + p] = v1[i].w; } }
    }
    for (int off = 32; off > 0; off >>= 1) {
      sum0 += __shfl_down(sum0, off, 64);
      sum1 += __shfl_down(sum1, off, 64);
    }
    int wave = t >> 6;
    if ((t & 63) == 0) { s_part[wave] = sum0; s_part[4 + wave] = sum1; }
    __syncthreads();
    if (t == 0) {
      float t0 = s_part[0] + s_part[1] + s_part[2] + s_part[3];
      float t1 = s_part[4] + s_part[5] + s_part[6] + s_part[7];
      dinv[row0] = rsqrtf(t0);
      dinv[row1] = rsqrtf(t1);
      int c0 = s_cnt[0], c1 = s_cnt[1];
      nnz[row0] = (c0 > MAXDEG) ? MAXDEG : c0;
      nnz[row1] = (c1 > MAXDEG) ? MAXDEG : c1;
    }
    return;
  }

  // ---------------- GEMM path: 128x64 tile, BK=64, bf16 MFMA (R15) ---------
  unsigned short* As = (unsigned short*)smem;               // [128][64] bf16
  unsigned short* Bs = (unsigned short*)(smem + 16 * 1024); // [64][64] bf16 (B^T)
  int mb = blockIdx.x >> 2, nb = blockIdx.x & 3;
  int m0 = mb * 128, n0 = nb * 64;
  int w = t >> 6, l = t & 63;

  f32x4 acc[2][4] = {};

  for (int kt = 0; kt < EMB; kt += 64) {
    __syncthreads();
    {
      int c4 = t & 15;
#pragma unroll
      for (int rr = 0; rr < 8; rr++) {
        int row = rr * 16 + (t >> 4);
        float4 v = *(const float4*)&X[(size_t)(m0 + row) * EMB + kt + c4 * 4];
        u16x4 pk = {f2bf(v.x), f2bf(v.y), f2bf(v.z), f2bf(v.w)};
        int slot = ((c4 >> 1) + (row >> 1)) & 7;
        *(u16x4*)&As[row * 64 + slot * 8 + (c4 & 1) * 4] = pk;
      }
    }
    {
      int n = t >> 2, q = t & 3;
      const unsigned short* src = &Wt[(size_t)(n0 + n) * EMB + kt + q * 16];
#pragma unroll
      for (int e = 0; e < 2; e++) {
        u16x8 v = *(const u16x8*)(src + e * 8);
        int slot = ((q * 2 + e) + (n >> 1)) & 7;
        *(u16x8*)&Bs[n * 64 + slot * 8] = v;
      }
    }
    __syncthreads();
#pragma unroll
    for (int ks = 0; ks < 2; ks++) {
      bf16x8v a[2], b[4];
#pragma unroll
      for (int mf = 0; mf < 2; mf++) {
        int row = w * 32 + mf * 16 + (l & 15);
        int slot = ((ks * 4 + (l >> 4)) + (row >> 1)) & 7;
        a[mf] = *(bf16x8v*)&As[row * 64 + slot * 8];
      }
#pragma unroll
      for (int nf = 0; nf < 4; nf++) {
        int rowB = nf * 16 + (l & 15);
        int slot = ((ks * 4 + (l >> 4)) + (rowB >> 1)) & 7;
        b[nf] = *(bf16x8v*)&Bs[rowB * 64 + slot * 8];
      }
#pragma unroll
      for (int mf = 0; mf < 2; mf++)
#pragma unroll
        for (int nf = 0; nf < 4; nf++)
          acc[mf][nf] = __builtin_amdgcn_mfma_f32_16x16x32_bf16(a[mf], b[nf], acc[mf][nf], 0, 0, 0);
    }
  }
#pragma unroll
  for (int mf = 0; mf < 2; mf++)
#pragma unroll
    for (int nf = 0; nf < 4; nf++) {
      int r0 = m0 + w * 32 + mf * 16 + (l >> 4) * 4;
      int cc = n0 + nf * 16 + (l & 15);
      float bv = bias[cc];
#pragma unroll
      for (int r = 0; r < 4; r++)
        hb0[(size_t)(r0 + r) * HID + cc] = f2bf(fmaxf(acc[mf][nf][r] + bv, 0.f));
    }
}

// ---------------------------------------------------------------------------
// One APPNP step (R15 verbatim): bf16/f32, dinv folded, edge-prefetched
// n<=4 fast path (poison-safe clamp), serial tail for rare n>4.
// ---------------------------------------------------------------------------
__global__ __launch_bounds__(256) void prop_bf16(
    const unsigned short* __restrict__ h_in, const unsigned short* __restrict__ hb0,
    unsigned short* __restrict__ h_out, const float* __restrict__ dinv,
    const int* __restrict__ nnz, const int* __restrict__ cols,
    const float* __restrict__ vals) {
  int wave = threadIdx.x >> 6;
  int lane = threadIdx.x & 63;
  int row = blockIdx.x * 4 + wave;

  int n = nnz[row];
  int base = row * MAXDEG;

  u16x4 h0v = *(const u16x4*)&hb0[(size_t)row * HID + lane * 4];
  int4   cv = *(const int4*)&cols[base];
  float4 vv = *(const float4*)&vals[base];

  int jj[4]; float ww[4];
  jj[0] = (0 < n) ? cv.x : row;  ww[0] = (0 < n) ? vv.x : 0.f;
  jj[1] = (1 < n) ? cv.y : row;  ww[1] = (1 < n) ? vv.y : 0.f;
  jj[2] = (2 < n) ? cv.z : row;  ww[2] = (2 < n) ? vv.z : 0.f;
  jj[3] = (3 < n) ? cv.w : row;  ww[3] = (3 < n) ? vv.w : 0.f;

  float ax = 0.f, ay = 0.f, az = 0.f, aw = 0.f;
#pragma unroll
  for (int k = 0; k < 4; k++) {
    float wgt = ww[k] * dinv[jj[k]];
    u16x4 hv = *(const u16x4*)&h_in[(size_t)jj[k] * HID + lane * 4];
    ax += wgt * bf2f(hv[0]); ay += wgt * bf2f(hv[1]);
    az += wgt * bf2f(hv[2]); aw += wgt * bf2f(hv[3]);
  }
  for (int k = 4; k < n; k++) {          // rare
    int j = cols[base + k];
    float wgt = vals[base + k] * dinv[j];
    u16x4 hv = *(const u16x4*)&h_in[(size_t)j * HID + lane * 4];
    ax += wgt * bf2f(hv[0]); ay += wgt * bf2f(hv[1]);
    az += wgt * bf2f(hv[2]); aw += wgt * bf2f(hv[3]);
  }
  float s = 0.8f * dinv[row];
  u16x4 o;
  o[0] = f2bf(s * ax + 0.2f * bf2f(h0v[0]));
  o[1] = f2bf(s * ay + 0.2f * bf2f(h0v[1]));
  o[2] = f2bf(s * az + 0.2f * bf2f(h0v[2]));
  o[3] = f2bf(s * aw + 0.2f * bf2f(h0v[3]));
  *(u16x4*)&h_out[(size_t)row * HID + lane * 4] = o;
}

// Final step: identical math, f32 output to d_out. (R15 verbatim)
__global__ __launch_bounds__(256) void prop_final(
    const unsigned short* __restrict__ h_in, const unsigned short* __restrict__ hb0,
    float* __restrict__ out, const float* __restrict__ dinv,
    const int* __restrict__ nnz, const int* __restrict__ cols,
    const float* __restrict__ vals) {
  int wave = threadIdx.x >> 6;
  int lane = threadIdx.x & 63;
  int row = blockIdx.x * 4 + wave;

  int n = nnz[row];
  int base = row * MAXDEG;

  u16x4 h0v = *(const u16x4*)&hb0[(size_t)row * HID + lane * 4];
  int4   cv = *(const int4*)&cols[base];
  float4 vv = *(const float4*)&vals[base];

  int jj[4]; float ww[4];
  jj[0] = (0 < n) ? cv.x : row;  ww[0] = (0 < n) ? vv.x : 0.f;
  jj[1] = (1 < n) ? cv.y : row;  ww[1] = (1 < n) ? vv.y : 0.f;
  jj[2] = (2 < n) ? cv.z : row;  ww[2] = (2 < n) ? vv.z : 0.f;
  jj[3] = (3 < n) ? cv.w : row;  ww[3] = (3 < n) ? vv.w : 0.f;

  float ax = 0.f, ay = 0.f, az = 0.f, aw = 0.f;
#pragma unroll
  for (int k = 0; k < 4; k++) {
    float wgt = ww[k] * dinv[jj[k]];
    u16x4 hv = *(const u16x4*)&h_in[(size_t)jj[k] * HID + lane * 4];
    ax += wgt * bf2f(hv[0]); ay += wgt * bf2f(hv[1]);
    az += wgt * bf2f(hv[2]); aw += wgt * bf2f(hv[3]);
  }
  for (int k = 4; k < n; k++) {          // rare
    int j = cols[base + k];
    float wgt = vals[base + k] * dinv[j];
    u16x4 hv = *(const u16x4*)&h_in[(size_t)j * HID + lane * 4];
    ax += wgt * bf2f(hv[0]); ay += wgt * bf2f(hv[1]);
    az += wgt * bf2f(hv[2]); aw += wgt * bf2f(hv[3]);
  }
  float s = 0.8f * dinv[row];
  float4 o;
  o.x = s * ax + 0.2f * bf2f(h0v[0]);
  o.y = s * ay + 0.2f * bf2f(h0v[1]);
  o.z = s * az + 0.2f * bf2f(h0v[2]);
  o.w = s * aw + 0.2f * bf2f(h0v[3]);
  *(float4*)&out[(size_t)row * HID + lane * 4] = o;
}

// ---------------------------------------------------------------------------
extern "C" void kernel_launch(void* const* d_in, const int* in_sizes, int n_in,
                              void* d_out, int out_size, void* d_ws, size_t ws_size,
                              hipStream_t stream) {
  const float* X    = (const float*)d_in[0];  // [8192,1024]
  const float* W    = (const float*)d_in[1];  // [1024,256]
  const float* bias = (const float*)d_in[2];  // [256]
  const float* adj  = (const float*)d_in[3];  // [8192,8192]
  float* out = (float*)d_out;                 // [8192,256]

  char* ws = (char*)d_ws;
  unsigned short* hb0  = (unsigned short*)(ws);                           // 4 MB
  unsigned short* hb1  = (unsigned short*)(ws + (size_t)4 * 1024 * 1024); // 4 MB
  unsigned short* hb2  = (unsigned short*)(ws + (size_t)8 * 1024 * 1024); // 4 MB
  float* dinv = (float*)(ws + (size_t)12 * 1024 * 1024);                  // 32 KB
  int*   nnz  = (int*)  (ws + (size_t)12 * 1024 * 1024 + 32 * 1024);      // 32 KB
  int*   cols = (int*)  (ws + (size_t)12 * 1024 * 1024 + 64 * 1024);      // 4 MB
  float* vals = (float*)(ws + (size_t)16 * 1024 * 1024 + 64 * 1024);      // 4 MB
  unsigned short* Wt = (unsigned short*)(ws + (size_t)20 * 1024 * 1024
                                            + 64 * 1024);                 // 512 KB

  prep_wt<<<64, 256, 0, stream>>>(W, Wt);
  fused_extract_gemm<<<GEMM_BLOCKS + NNODES / 2, 256, 0, stream>>>(
      X, Wt, bias, adj, hb0, dinv, nnz, cols, vals);

  // 5 bf16 steps ping-ponging hb1/hb2, then final f32 step into d_out.
  prop_bf16<<<NNODES / 4, 256, 0, stream>>>(hb0, hb0, hb1, dinv, nnz, cols, vals);
  prop_bf16<<<NNODES / 4, 256, 0, stream>>>(hb1, hb0, hb2, dinv, nnz, cols, vals);
  prop_bf16<<<NNODES / 4, 256, 0, stream>>>(hb2, hb0, hb1, dinv, nnz, cols, vals);
  prop_bf16<<<NNODES / 4, 256, 0, stream>>>(hb1, hb0, hb2, dinv, nnz, cols, vals);
  prop_bf16<<<NNODES / 4, 256, 0, stream>>>(hb2, hb0, hb1, dinv, nnz, cols, vals);
  prop_final<<<NNODES / 4, 256, 0, stream>>>(hb1, hb0, out, dinv, nnz, cols, vals);
}